// Round 12
// baseline (252.189 us; speedup 1.0000x reference)
//
#include <hip/hip_runtime.h>
#include <hip/hip_bf16.h>

#define NB 8
#define NS 4096
#define ND 1280
#define NR 64
#define EW 6656   // D + R*R + D

#define AS1 __attribute__((address_space(1)))
#define AS3 __attribute__((address_space(3)))

typedef __attribute__((ext_vector_type(4))) float f4;
typedef __attribute__((ext_vector_type(8))) short bf8;

union BF8U { bf8 v; unsigned u[4]; };

__device__ __forceinline__ unsigned short f2bf(float f) {
  union { float f; unsigned u; } v; v.f = f;
  unsigned u = v.u + 0x7FFFu + ((v.u >> 16) & 1u);  // RNE
  return (unsigned short)(u >> 16);
}

__device__ __forceinline__ unsigned pk2(float a, float b) {
  __hip_bfloat162 t = __float22bfloat162_rn(float2{a, b});   // v_cvt_pk_bf16_f32
  return *reinterpret_cast<unsigned*>(&t);
}

// ---------------- prep: W2F, W3FB (per-batch, up_w folded), h2bias ----------------
__global__ __launch_bounds__(256) void prep_all(const float* __restrict__ embed,
                                                const float* __restrict__ w_down,
                                                const float* __restrict__ w_up,
                                                const float* __restrict__ b_down,
                                                unsigned short* __restrict__ W2F,
                                                unsigned short* __restrict__ W3FB,
                                                float* __restrict__ h2bias) {
  const int blk = blockIdx.x;
  const int t   = threadIdx.x;
  if (blk < 160) {
    const int b  = blk / 20;
    const int qg = (blk % 20) / 5;
    const int dg = blk % 5;
    __shared__ float mids[16][64];
    #pragma unroll
    for (int i = 0; i < 4; ++i) {
      int idx = t + i * 256;
      mids[idx >> 6][idx & 63] = embed[b * EW + ND + qg * 1024 + idx];
    }
    __syncthreads();
    const int d = dg * 256 + t;
    float acc[16];
    #pragma unroll
    for (int q = 0; q < 16; ++q) acc[q] = 0.f;
    for (int r = 0; r < 64; r += 8) {
      float wd[8];
      #pragma unroll
      for (int u = 0; u < 8; ++u) wd[u] = w_down[(r + u) * ND + d];
      #pragma unroll
      for (int u = 0; u < 8; ++u)
        #pragma unroll
        for (int q = 0; q < 16; ++q) acc[q] += mids[q][r + u] * wd[u];
    }
    const float dwn = embed[b * EW + d];
    const int kt = d >> 5, lanehi = (d & 31) >> 3, jj = d & 7;
    #pragma unroll
    for (int q = 0; q < 16; ++q)
      W2F[(((b * 40 + kt) * 4 + qg) << 9) + (lanehi * 16 + q) * 8 + jj] = f2bf(acc[q] * dwn);
  } else if (blk < 2720) {
    const int local = blk - 160;
    const int b  = local / 320;
    const int g  = (local % 320) * 256 + t;   // g = d*64 + q
    const int d  = g >> 6, q = g & 63;
    const int kt = q >> 5, dt = d >> 4;
    const int lanei = ((q & 31) >> 3) * 16 + (d & 15), jj = q & 7;
    const float upw = embed[b * EW + 5376 + d];
    W3FB[(size_t)b * 81920 + ((kt * 80 + dt) * 64 + lanei) * 8 + jj] = f2bf(w_up[g] * upw);
  } else {
    #pragma unroll
    for (int ii = 0; ii < 2; ++ii) {
      int id = ii * 256 + t;                  // id = b*64 + q
      int bb = id >> 6, q = id & 63;
      float s = 0.f;
      for (int r = 0; r < 64; ++r) s += b_down[r] * embed[bb * EW + ND + q * 64 + r];
      h2bias[id] = s;
    }
  }
}

// ---------------- kA (x4 bisect loop): x -> h2 frags ----------------
// MEASUREMENT ROUND: body repeated 4x (idempotent — identical values rewritten)
// so the dispatch exceeds the harness fill kernels (~95us) and appears in
// top-5 with counters. Per-rep time = dur/4.
__global__ __launch_bounds__(512, 4) void kA(const float* __restrict__ x,
                                             const unsigned short* __restrict__ W2F,
                                             const float* __restrict__ h2bias,
                                             unsigned* __restrict__ h2F) {
  const int tid  = threadIdx.x;
  const int lane = tid & 63;
  const int w    = tid >> 6;            // 0..7
  const int b    = blockIdx.x >> 8;
  const int tile = blockIdx.x & 255;
  const int lo16 = lane & 15;
  const int hi4  = lane >> 4;

  // pool: xs [2][16][260] f32 (33,280 B)  aliased by  part [8][16][66] f32 (33,792 B)
  __shared__ __align__(16) char pool[33856];
  float (*xs)[16][260]  = (float (*)[16][260])pool;
  float (*part)[16][66] = (float (*)[16][66])pool;

  const float* xrow0 = x + ((size_t)b * NS + tile * 16) * ND;
  const unsigned short* w2b = W2F + (size_t)b * 81920;

  #define DMA_A(c, buf)                                                              \
    _Pragma("unroll")                                                                \
    for (int i = 0; i < 2; ++i) {                                                    \
      const int r = 2 * w + i;                                                       \
      const float* src = xrow0 + (size_t)r * ND + (c) * 256 + lane * 4;              \
      __builtin_amdgcn_global_load_lds((AS1 void*)src,                               \
          (AS3 void*)&xs[buf][r][0], 16, 0, 0);                                      \
    }

  for (int rep = 0; rep < 4; ++rep) {
    __syncthreads();                    // prior rep's part-reads done; xs safe to overwrite
    DMA_A(0, 0)
    f4 acc[4] = {};
    for (int c = 0; c < 5; ++c) {
      const int buf = c & 1;
      asm volatile("s_waitcnt vmcnt(0)" ::: "memory");   // my DMA(c) landed
      __syncthreads();                                   // everyone's DMA(c) landed
      const int kt = c * 8 + w;
      const unsigned short* wp = w2b + ((kt * 4) << 9) + lane * 8;
      bf8 bw0 = *(const bf8*)(wp);
      bf8 bw1 = *(const bf8*)(wp + (1 << 9));
      bf8 bw2 = *(const bf8*)(wp + (2 << 9));
      bf8 bw3 = *(const bf8*)(wp + (3 << 9));
      if (c < 4) DMA_A(c + 1, buf ^ 1)
      f4 a0 = *(const f4*)&xs[buf][lo16][w * 32 + hi4 * 8];
      f4 a1 = *(const f4*)&xs[buf][lo16][w * 32 + hi4 * 8 + 4];
      BF8U af;
      af.u[0] = pk2(a0[0], a0[1]); af.u[1] = pk2(a0[2], a0[3]);
      af.u[2] = pk2(a1[0], a1[1]); af.u[3] = pk2(a1[2], a1[3]);
      acc[0] = __builtin_amdgcn_mfma_f32_16x16x32_bf16(af.v, bw0, acc[0], 0, 0, 0);
      acc[1] = __builtin_amdgcn_mfma_f32_16x16x32_bf16(af.v, bw1, acc[1], 0, 0, 0);
      acc[2] = __builtin_amdgcn_mfma_f32_16x16x32_bf16(af.v, bw2, acc[2], 0, 0, 0);
      acc[3] = __builtin_amdgcn_mfma_f32_16x16x32_bf16(af.v, bw3, acc[3], 0, 0, 0);
    }

    __syncthreads();   // xs fully consumed; pool becomes part

    #pragma unroll
    for (int nt = 0; nt < 4; ++nt)
      #pragma unroll
      for (int j = 0; j < 4; ++j)
        part[w][hi4 * 4 + j][nt * 16 + lo16] = acc[nt][j];
    __syncthreads();

    {
      const int s  = tid >> 5;            // 0..15
      const int q0 = (tid & 31) * 2;      // 0..62
      float v0 = h2bias[b * 64 + q0];
      float v1 = h2bias[b * 64 + q0 + 1];
      #pragma unroll
      for (int ww = 0; ww < 8; ++ww) {
        v0 += part[ww][s][q0];
        v1 += part[ww][s][q0 + 1];
      }
      const unsigned pk = pk2(v0, v1);
      const int kt2   = q0 >> 5;
      const int lanei = ((q0 & 31) >> 3) * 16 + s;
      const int u     = (q0 & 7) >> 1;
      h2F[(size_t)blockIdx.x * 512 + (kt2 * 64 + lanei) * 4 + u] = pk;
    }
  }
}

// ---------------- kB (x4 bisect loop): h2 frags -> out ----------------
__global__ __launch_bounds__(512, 2) void kB(const unsigned* __restrict__ h2F,
                                             const float* __restrict__ embed,
                                             const float* __restrict__ b_up,
                                             const unsigned short* __restrict__ W3FB,
                                             float* __restrict__ out) {
  const int tid  = threadIdx.x;
  const int lane = tid & 63;
  const int w    = tid >> 6;
  const int b    = blockIdx.x >> 8;
  const int tile = blockIdx.x & 255;
  const int lo16 = lane & 15;
  const int hi4  = lane >> 4;

  __shared__ __align__(16) float outS[16][1284];
  __shared__ __align__(16) float pbs[1280];

  const unsigned short* w3b = W3FB + (size_t)b * 81920;

  for (int rep = 0; rep < 4; ++rep) {
    __syncthreads();                    // prior rep's flush reads done; outS/pbs safe
    {
      const float* upw = embed + b * EW + 5376;
      for (int i = tid; i < 1280; i += 512) pbs[i] = b_up[i] * upw[i];
    }
    BF8U ha0, ha1;
    {
      const unsigned* hp = h2F + (size_t)blockIdx.x * 512;
      uint4 h0 = *(const uint4*)(hp + (0 * 64 + lane) * 4);
      uint4 h1 = *(const uint4*)(hp + (1 * 64 + lane) * 4);
      ha0.u[0] = h0.x; ha0.u[1] = h0.y; ha0.u[2] = h0.z; ha0.u[3] = h0.w;
      ha1.u[0] = h1.x; ha1.u[1] = h1.y; ha1.u[2] = h1.z; ha1.u[3] = h1.w;
    }

    int dt = w * 10;
    bf8 wb0 = *(const bf8*)(w3b + (size_t)(dt * 64 + lane) * 8);
    bf8 wb1 = *(const bf8*)(w3b + (size_t)((80 + dt) * 64 + lane) * 8);

    for (int i = 0; i < 10; ++i) {
      bf8 wn0, wn1;
      if (i < 9) {
        wn0 = *(const bf8*)(w3b + (size_t)((dt + 1) * 64 + lane) * 8);
        wn1 = *(const bf8*)(w3b + (size_t)((80 + dt + 1) * 64 + lane) * 8);
      }
      f4 o = {};
      o = __builtin_amdgcn_mfma_f32_16x16x32_bf16(wb0, ha0.v, o, 0, 0, 0);
      o = __builtin_amdgcn_mfma_f32_16x16x32_bf16(wb1, ha1.v, o, 0, 0, 0);
      *(f4*)&outS[lo16][dt * 16 + hi4 * 4] = o;
      wb0 = wn0; wb1 = wn1;
      ++dt;
    }

    __syncthreads();

    // linear flush: wave w writes rows 2w, 2w+1; per row 5 x 1KB contiguous
    #pragma unroll
    for (int i = 0; i < 2; ++i) {
      const int r = 2 * w + i;
      float* orow = out + ((size_t)b * NS + tile * 16 + r) * ND;
      #pragma unroll
      for (int c = 0; c < 5; ++c) {
        const int col = c * 256 + lane * 4;
        f4 v = *(const f4*)&outS[r][col];
        f4 p = *(const f4*)&pbs[col];
        f4 rr;
        #pragma unroll
        for (int j = 0; j < 4; ++j) rr[j] = v[j] + p[j];
        *(f4*)(orow + col) = rr;
      }
    }
  }
}

extern "C" void kernel_launch(void* const* d_in, const int* in_sizes, int n_in,
                              void* d_out, int out_size, void* d_ws, size_t ws_size,
                              hipStream_t stream) {
  const float* x      = (const float*)d_in[0];
  const float* embed  = (const float*)d_in[1];
  const float* w_down = (const float*)d_in[2];
  const float* b_down = (const float*)d_in[3];
  const float* w_up   = (const float*)d_in[4];
  const float* b_up   = (const float*)d_in[5];
  float* out = (float*)d_out;

  char* ws = (char*)d_ws;
  unsigned short* W2F  = (unsigned short*)ws;                // 1,310,720 B
  unsigned short* W3FB = (unsigned short*)(ws + 1310720);    // 1,310,720 B
  float* h2bias        = (float*)(ws + 2621440);             //     2,048 B
  unsigned* h2F        = (unsigned*)(ws + 2623488);          // 4,194,304 B

  prep_all<<<2721, 256, 0, stream>>>(embed, w_down, w_up, b_down, W2F, W3FB, h2bias);
  kA<<<2048, 512, 0, stream>>>(x, W2F, h2bias, h2F);
  kB<<<2048, 512, 0, stream>>>(h2F, embed, b_up, W3FB, out);
}

// Round 13
// 112.692 us; speedup vs baseline: 2.2378x; 2.2378x over previous
//
#include <hip/hip_runtime.h>
#include <hip/hip_bf16.h>

#define NB 8
#define NS 4096
#define ND 1280
#define NR 64
#define EW 6656   // D + R*R + D

#define AS1 __attribute__((address_space(1)))
#define AS3 __attribute__((address_space(3)))

typedef __attribute__((ext_vector_type(4))) float f4;
typedef __attribute__((ext_vector_type(8))) short bf8;

union BF8U { bf8 v; unsigned u[4]; };

__device__ __forceinline__ unsigned short f2bf(float f) {
  union { float f; unsigned u; } v; v.f = f;
  unsigned u = v.u + 0x7FFFu + ((v.u >> 16) & 1u);  // RNE
  return (unsigned short)(u >> 16);
}

__device__ __forceinline__ unsigned pk2(float a, float b) {
  __hip_bfloat162 t = __float22bfloat162_rn(float2{a, b});   // v_cvt_pk_bf16_f32
  return *reinterpret_cast<unsigned*>(&t);
}

// ---------------- prep: W2F, W3FB (per-batch, up_w folded), h2bias ----------------
__global__ __launch_bounds__(256) void prep_all(const float* __restrict__ embed,
                                                const float* __restrict__ w_down,
                                                const float* __restrict__ w_up,
                                                const float* __restrict__ b_down,
                                                unsigned short* __restrict__ W2F,
                                                unsigned short* __restrict__ W3FB,
                                                float* __restrict__ h2bias) {
  const int blk = blockIdx.x;
  const int t   = threadIdx.x;
  if (blk < 160) {
    const int b  = blk / 20;
    const int qg = (blk % 20) / 5;
    const int dg = blk % 5;
    __shared__ float mids[16][64];
    #pragma unroll
    for (int i = 0; i < 4; ++i) {
      int idx = t + i * 256;
      mids[idx >> 6][idx & 63] = embed[b * EW + ND + qg * 1024 + idx];
    }
    __syncthreads();
    const int d = dg * 256 + t;
    float acc[16];
    #pragma unroll
    for (int q = 0; q < 16; ++q) acc[q] = 0.f;
    for (int r = 0; r < 64; r += 8) {
      float wd[8];
      #pragma unroll
      for (int u = 0; u < 8; ++u) wd[u] = w_down[(r + u) * ND + d];
      #pragma unroll
      for (int u = 0; u < 8; ++u)
        #pragma unroll
        for (int q = 0; q < 16; ++q) acc[q] += mids[q][r + u] * wd[u];
    }
    const float dwn = embed[b * EW + d];
    const int kt = d >> 5, lanehi = (d & 31) >> 3, jj = d & 7;
    #pragma unroll
    for (int q = 0; q < 16; ++q)
      W2F[(((b * 40 + kt) * 4 + qg) << 9) + (lanehi * 16 + q) * 8 + jj] = f2bf(acc[q] * dwn);
  } else if (blk < 2720) {
    const int local = blk - 160;
    const int b  = local / 320;
    const int g  = (local % 320) * 256 + t;   // g = d*64 + q
    const int d  = g >> 6, q = g & 63;
    const int kt = q >> 5, dt = d >> 4;
    const int lanei = ((q & 31) >> 3) * 16 + (d & 15), jj = q & 7;
    const float upw = embed[b * EW + 5376 + d];
    W3FB[(size_t)b * 81920 + ((kt * 80 + dt) * 64 + lanei) * 8 + jj] = f2bf(w_up[g] * upw);
  } else {
    #pragma unroll
    for (int ii = 0; ii < 2; ++ii) {
      int id = ii * 256 + t;                  // id = b*64 + q
      int bb = id >> 6, q = id & 63;
      float s = 0.f;
      for (int r = 0; r < 64; ++r) s += b_down[r] * embed[bb * EW + ND + q * 64 + r];
      h2bias[id] = s;
    }
  }
}

// ---------------- kA: x -> h2 frags, DEEP-PIPELINED ----------------
// R13: raw s_barrier (no compiler vmcnt(0) drain) + counted vmcnt + 4 LDS
// buffers. Two chunks (6KB/wave) stay in flight across every barrier.
// Hand-unrolled 5-chunk loop -> all waits/buffers compile-time static.
// Row stride 268 floats (1072B): A-frag ds_read conflicts 8-way -> ~4-way.
__global__ __launch_bounds__(512, 4) void kA(const float* __restrict__ x,
                                             const unsigned short* __restrict__ W2F,
                                             const float* __restrict__ h2bias,
                                             unsigned* __restrict__ h2F) {
  const int tid  = threadIdx.x;
  const int lane = tid & 63;
  const int w    = tid >> 6;            // 0..7
  const int b    = blockIdx.x >> 8;
  const int tile = blockIdx.x & 255;
  const int lo16 = lane & 15;
  const int hi4  = lane >> 4;

  // pool: xs[4][16][268] f32 (68,608 B); part[8][16][66] (33,792 B) aliases it
  __shared__ __align__(16) char pool[68608];
  float (*xs)[16][268]  = (float (*)[16][268])pool;
  float (*part)[16][66] = (float (*)[16][66])pool;

  const float* xrow0 = x + ((size_t)b * NS + tile * 16) * ND;
  const unsigned short* w2b = W2F + (size_t)b * 81920;

  // wave w DMAs rows 2w, 2w+1 of chunk c; each instr = 1KB of ONE row
  #define DMA_A(c, buf)                                                              \
    _Pragma("unroll")                                                                \
    for (int i = 0; i < 2; ++i) {                                                    \
      const int r = 2 * w + i;                                                       \
      const float* src = xrow0 + (size_t)r * ND + (c) * 256 + lane * 4;              \
      __builtin_amdgcn_global_load_lds((AS1 void*)src,                               \
          (AS3 void*)&xs[buf][r][0], 16, 0, 0);                                      \
    }

  // B-frags for chunk c (4 x 16B per lane, L2-hot)
  #define LOADB(dst, c) {                                                            \
    const unsigned short* wp = w2b + ((((c) * 8 + w) * 4) << 9) + lane * 8;          \
    dst[0] = *(const bf8*)(wp);                                                      \
    dst[1] = *(const bf8*)(wp + (1 << 9));                                           \
    dst[2] = *(const bf8*)(wp + (2 << 9));                                           \
    dst[3] = *(const bf8*)(wp + (3 << 9));                                           \
  }

  #define COMPUTE(c, bwX) {                                                          \
    f4 a0 = *(const f4*)&xs[(c) & 3][lo16][w * 32 + hi4 * 8];                        \
    f4 a1 = *(const f4*)&xs[(c) & 3][lo16][w * 32 + hi4 * 8 + 4];                    \
    BF8U af;                                                                         \
    af.u[0] = pk2(a0[0], a0[1]); af.u[1] = pk2(a0[2], a0[3]);                        \
    af.u[2] = pk2(a1[0], a1[1]); af.u[3] = pk2(a1[2], a1[3]);                        \
    acc[0] = __builtin_amdgcn_mfma_f32_16x16x32_bf16(af.v, bwX[0], acc[0], 0, 0, 0); \
    acc[1] = __builtin_amdgcn_mfma_f32_16x16x32_bf16(af.v, bwX[1], acc[1], 0, 0, 0); \
    acc[2] = __builtin_amdgcn_mfma_f32_16x16x32_bf16(af.v, bwX[2], acc[2], 0, 0, 0); \
    acc[3] = __builtin_amdgcn_mfma_f32_16x16x32_bf16(af.v, bwX[3], acc[3], 0, 0, 0); \
  }

  f4 acc[4] = {};
  bf8 b0f[4], b1f[4], b2f[4], b3f[4], b4f[4];

  // prologue issue order (vmem): D0(2) D1(2) b0(4) D2(2) b1(4)  = 14 ops
  DMA_A(0, 0)
  DMA_A(1, 1)
  LOADB(b0f, 0)
  DMA_A(2, 2)
  LOADB(b1f, 1)

  // iter 0: drain {D0,D1,b0}, keep {D2,b1}; then issue D3, b2
  asm volatile("s_waitcnt vmcnt(6)" ::: "memory");
  __builtin_amdgcn_s_barrier();          // raw: no compiler vmcnt drain
  DMA_A(3, 3)
  LOADB(b2f, 2)
  COMPUTE(0, b0f)

  // iter 1: drain {D2,b1}, keep {D3,b2}; issue D4 (buf0: chunk0 reads done via barrier), b3
  asm volatile("s_waitcnt vmcnt(6)" ::: "memory");
  __builtin_amdgcn_s_barrier();
  DMA_A(4, 0)
  LOADB(b3f, 3)
  COMPUTE(1, b1f)

  // iter 2: drain {D3,b2}, keep {D4,b3}; issue b4
  asm volatile("s_waitcnt vmcnt(6)" ::: "memory");
  __builtin_amdgcn_s_barrier();
  LOADB(b4f, 4)
  COMPUTE(2, b2f)

  // iter 3: drain {D4,b3}, keep {b4}
  asm volatile("s_waitcnt vmcnt(4)" ::: "memory");
  __builtin_amdgcn_s_barrier();
  COMPUTE(3, b3f)

  // iter 4: drain {b4}
  asm volatile("s_waitcnt vmcnt(0)" ::: "memory");
  __builtin_amdgcn_s_barrier();
  COMPUTE(4, b4f)

  __syncthreads();   // full drain OK here (loop done); pool becomes part

  // C/D: col q = nt*16+lo16, row s = hi4*4+j
  #pragma unroll
  for (int nt = 0; nt < 4; ++nt)
    #pragma unroll
    for (int j = 0; j < 4; ++j)
      part[w][hi4 * 4 + j][nt * 16 + lo16] = acc[nt][j];
  __syncthreads();

  // combine 8 partials + bias, emit bf16 frag (2KB contiguous per block)
  {
    const int s  = tid >> 5;            // 0..15
    const int q0 = (tid & 31) * 2;      // 0..62
    float v0 = h2bias[b * 64 + q0];
    float v1 = h2bias[b * 64 + q0 + 1];
    #pragma unroll
    for (int ww = 0; ww < 8; ++ww) {
      v0 += part[ww][s][q0];
      v1 += part[ww][s][q0 + 1];
    }
    const unsigned pk = pk2(v0, v1);
    const int kt2   = q0 >> 5;
    const int lanei = ((q0 & 31) >> 3) * 16 + s;
    const int u     = (q0 & 7) >> 1;
    h2F[(size_t)blockIdx.x * 512 + (kt2 * 64 + lanei) * 4 + u] = pk;
  }
}

// ---------------- kB: h2 frags -> out (unchanged R11 single-shot; ~floor) ----------------
__global__ __launch_bounds__(512, 2) void kB(const unsigned* __restrict__ h2F,
                                             const float* __restrict__ embed,
                                             const float* __restrict__ b_up,
                                             const unsigned short* __restrict__ W3FB,
                                             float* __restrict__ out) {
  const int tid  = threadIdx.x;
  const int lane = tid & 63;
  const int w    = tid >> 6;
  const int b    = blockIdx.x >> 8;
  const int tile = blockIdx.x & 255;
  const int lo16 = lane & 15;
  const int hi4  = lane >> 4;

  __shared__ __align__(16) float outS[16][1284];
  __shared__ __align__(16) float pbs[1280];

  {
    const float* upw = embed + b * EW + 5376;
    for (int i = tid; i < 1280; i += 512) pbs[i] = b_up[i] * upw[i];
  }

  BF8U ha0, ha1;
  {
    const unsigned* hp = h2F + (size_t)blockIdx.x * 512;
    uint4 h0 = *(const uint4*)(hp + (0 * 64 + lane) * 4);
    uint4 h1 = *(const uint4*)(hp + (1 * 64 + lane) * 4);
    ha0.u[0] = h0.x; ha0.u[1] = h0.y; ha0.u[2] = h0.z; ha0.u[3] = h0.w;
    ha1.u[0] = h1.x; ha1.u[1] = h1.y; ha1.u[2] = h1.z; ha1.u[3] = h1.w;
  }

  const unsigned short* w3b = W3FB + (size_t)b * 81920;

  int dt = w * 10;
  bf8 wb0 = *(const bf8*)(w3b + (size_t)(dt * 64 + lane) * 8);
  bf8 wb1 = *(const bf8*)(w3b + (size_t)((80 + dt) * 64 + lane) * 8);

  for (int i = 0; i < 10; ++i) {
    bf8 wn0, wn1;
    if (i < 9) {
      wn0 = *(const bf8*)(w3b + (size_t)((dt + 1) * 64 + lane) * 8);
      wn1 = *(const bf8*)(w3b + (size_t)((80 + dt + 1) * 64 + lane) * 8);
    }
    f4 o = {};
    o = __builtin_amdgcn_mfma_f32_16x16x32_bf16(wb0, ha0.v, o, 0, 0, 0);
    o = __builtin_amdgcn_mfma_f32_16x16x32_bf16(wb1, ha1.v, o, 0, 0, 0);
    *(f4*)&outS[lo16][dt * 16 + hi4 * 4] = o;
    wb0 = wn0; wb1 = wn1;
    ++dt;
  }

  __syncthreads();

  // linear flush: wave w writes rows 2w, 2w+1; per row 5 x 1KB contiguous
  #pragma unroll
  for (int i = 0; i < 2; ++i) {
    const int r = 2 * w + i;
    float* orow = out + ((size_t)b * NS + tile * 16 + r) * ND;
    #pragma unroll
    for (int c = 0; c < 5; ++c) {
      const int col = c * 256 + lane * 4;
      f4 v = *(const f4*)&outS[r][col];
      f4 p = *(const f4*)&pbs[col];
      f4 rr;
      #pragma unroll
      for (int j = 0; j < 4; ++j) rr[j] = v[j] + p[j];
      *(f4*)(orow + col) = rr;
    }
  }
}

extern "C" void kernel_launch(void* const* d_in, const int* in_sizes, int n_in,
                              void* d_out, int out_size, void* d_ws, size_t ws_size,
                              hipStream_t stream) {
  const float* x      = (const float*)d_in[0];
  const float* embed  = (const float*)d_in[1];
  const float* w_down = (const float*)d_in[2];
  const float* b_down = (const float*)d_in[3];
  const float* w_up   = (const float*)d_in[4];
  const float* b_up   = (const float*)d_in[5];
  float* out = (float*)d_out;

  char* ws = (char*)d_ws;
  unsigned short* W2F  = (unsigned short*)ws;                // 1,310,720 B
  unsigned short* W3FB = (unsigned short*)(ws + 1310720);    // 1,310,720 B
  float* h2bias        = (float*)(ws + 2621440);             //     2,048 B
  unsigned* h2F        = (unsigned*)(ws + 2623488);          // 4,194,304 B

  prep_all<<<2721, 256, 0, stream>>>(embed, w_down, w_up, b_down, W2F, W3FB, h2bias);
  kA<<<2048, 512, 0, stream>>>(x, W2F, h2bias, h2F);
  kB<<<2048, 512, 0, stream>>>(h2F, embed, b_up, W3FB, out);
}